// Round 8
// baseline (689.218 us; speedup 1.0000x reference)
//
#include <hip/hip_runtime.h>

// SimpleGNN: B=4, N=512, D=128, L=2 — DIAGNOSTIC ROUND.
// Real pipeline = round-3 best (67.9us) verbatim. Appended: 3 REP=16 ablation
// kernels (scratch output, deterministic) to get per-structure counters into
// rocprof top-5 past the ~39us harness fills:
//   abl_stream = v5 msg inner loop x16   -> true msg-structure cost
//   abl_valu   = same minus VMEM x16     -> VALU + LDS-broadcast floor
//   abl_l2     = VMEM stream only x16    -> L2 BW/latency floor

constexpr int Bc = 4, Nc = 512, Dc = 128, Lc = 2;
constexpr int BN = Bc * Nc;  // 2048
constexpr int TI = 8;        // i-rows per msg block
constexpr int JS = 4;        // j-split factor (partial sums)
constexpr int JT = Nc / JS;  // 128 j's per block
constexpr int JH = JT / 2;   // 64 j's per half
constexpr int JB = 8;        // j's per staged tile (per half)
constexpr int NT = JH / JB;  // 8 tiles
constexpr int TN = 4;        // rows per lin block
constexpr int AREP = 16;     // ablation repeat factor

// --- weight transpose
__global__ void transpose_w_kernel(const float* __restrict__ w1,
                                   const float* __restrict__ w2,
                                   float* __restrict__ wiT,
                                   float* __restrict__ wjT,
                                   float* __restrict__ w2T) {
    int idx = blockIdx.x * blockDim.x + threadIdx.x;
    if (idx >= Lc * Dc * Dc) return;
    int l = idx / (Dc * Dc);
    int rem = idx - l * Dc * Dc;
    int d = rem / Dc;
    int o = rem - d * Dc;
    wiT[idx] = w1[(l * Dc + o) * (2 * Dc) + d];
    wjT[idx] = w1[(l * Dc + o) * (2 * Dc) + Dc + d];
    w2T[idx] = w2[(l * Dc + o) * Dc + d];
}

// --- first linear (round-3 winner)
__global__ __launch_bounds__(128) void gnn_lin1(const float* __restrict__ h,
                                                const float* __restrict__ wiT,
                                                const float* __restrict__ wjT,
                                                const float* __restrict__ b1,
                                                float* __restrict__ ai,
                                                float* __restrict__ aj) {
    __shared__ float hs[TN][Dc];
    const int o = threadIdx.x;
    const int r0 = blockIdx.x * TN;
#pragma unroll
    for (int t = 0; t < TN; ++t) hs[t][o] = h[(r0 + t) * Dc + o];
    __syncthreads();
    float acci[TN], accj[TN];
    const float bo = b1[o];
#pragma unroll
    for (int t = 0; t < TN; ++t) { acci[t] = bo; accj[t] = 0.f; }
    for (int d = 0; d < Dc; d += 4) {
        float wi[4], wj[4];
#pragma unroll
        for (int k = 0; k < 4; ++k) {
            wi[k] = wiT[(d + k) * Dc + o];
            wj[k] = wjT[(d + k) * Dc + o];
        }
#pragma unroll
        for (int t = 0; t < TN; ++t) {
            const float4 hv = *reinterpret_cast<const float4*>(&hs[t][d]);
            acci[t] = fmaf(hv.x, wi[0], acci[t]);
            acci[t] = fmaf(hv.y, wi[1], acci[t]);
            acci[t] = fmaf(hv.z, wi[2], acci[t]);
            acci[t] = fmaf(hv.w, wi[3], acci[t]);
            accj[t] = fmaf(hv.x, wj[0], accj[t]);
            accj[t] = fmaf(hv.y, wj[1], accj[t]);
            accj[t] = fmaf(hv.z, wj[2], accj[t]);
            accj[t] = fmaf(hv.w, wj[3], accj[t]);
        }
    }
#pragma unroll
    for (int t = 0; t < TN; ++t) {
        ai[(r0 + t) * Dc + o] = acci[t];
        aj[(r0 + t) * Dc + o] = accj[t];
    }
}

// --- msg (round-3 winner: double-buffered LDS tiles)
__global__ __launch_bounds__(256) void gnn_msg(const float* __restrict__ ai,
                                               const float* __restrict__ aj,
                                               const float* __restrict__ adj,
                                               float* __restrict__ sp,
                                               float* __restrict__ arowp) {
    __shared__ float ajs[2][2][JB][Dc];
    __shared__ float adjsT[JT][TI];

    const int tid = threadIdx.x;
    const int d = tid & 127;
    const int half = tid >> 7;
    const int js = blockIdx.x & (JS - 1);
    const int rblk = blockIdx.x >> 2;
    const int r0 = rblk * TI;
    const int b = r0 / Nc;
    const int i0 = r0 - b * Nc;
    const int j0 = js * JT;
    const int j0h = j0 + half * JH;
    const float* __restrict__ ajb = aj + b * Nc * Dc;
    const float* __restrict__ adjb = adj + (size_t)b * Nc * Nc;

    {
        const int rr = tid >> 5;
        const int c4 = (tid & 31) * 4;
        const float4 av = *reinterpret_cast<const float4*>(&adjb[(i0 + rr) * Nc + j0 + c4]);
        adjsT[c4 + 0][rr] = av.x;
        adjsT[c4 + 1][rr] = av.y;
        adjsT[c4 + 2][rr] = av.z;
        adjsT[c4 + 3][rr] = av.w;
        float ps = av.x + av.y + av.z + av.w;
#pragma unroll
        for (int m = 16; m >= 1; m >>= 1) ps += __shfl_xor(ps, m);
        if ((tid & 31) == 0) arowp[js * BN + r0 + rr] = ps;
    }

    float x[TI], acc[TI];
#pragma unroll
    for (int r = 0; r < TI; ++r) {
        x[r] = ai[(r0 + r) * Dc + d];
        acc[r] = 0.f;
    }

    const int jjA = d >> 5;
    const int jjB = jjA + 4;
    const int d4 = (d & 31) * 4;
    float4 pfA, pfB;

#define LOADTILE(tt)                                                             \
    {                                                                            \
        const float* base_ = ajb + (j0h + (tt) * JB) * Dc;                       \
        pfA = *reinterpret_cast<const float4*>(&base_[jjA * Dc + d4]);           \
        pfB = *reinterpret_cast<const float4*>(&base_[jjB * Dc + d4]);           \
    }
#define STORETILE(bf)                                                            \
    {                                                                            \
        *reinterpret_cast<float4*>(&ajs[half][bf][jjA][d4]) = pfA;               \
        *reinterpret_cast<float4*>(&ajs[half][bf][jjB][d4]) = pfB;               \
    }

    LOADTILE(0);
    STORETILE(0);
    LOADTILE(1);
    __syncthreads();

    for (int tt = 0; tt < NT; ++tt) {
        const int buf = tt & 1;
        if (tt + 1 < NT) {
            STORETILE(buf ^ 1);
            if (tt + 2 < NT) LOADTILE(tt + 2);
        }
        const int jg0 = half * JH + tt * JB;
#pragma unroll
        for (int jj = 0; jj < JB; ++jj) {
            const float v = ajs[half][buf][jj][d];
            const float4 a0 = *reinterpret_cast<const float4*>(&adjsT[jg0 + jj][0]);
            const float4 a1 = *reinterpret_cast<const float4*>(&adjsT[jg0 + jj][4]);
            acc[0] = fmaf(a0.x, fmaxf(x[0] + v, 0.f), acc[0]);
            acc[1] = fmaf(a0.y, fmaxf(x[1] + v, 0.f), acc[1]);
            acc[2] = fmaf(a0.z, fmaxf(x[2] + v, 0.f), acc[2]);
            acc[3] = fmaf(a0.w, fmaxf(x[3] + v, 0.f), acc[3]);
            acc[4] = fmaf(a1.x, fmaxf(x[4] + v, 0.f), acc[4]);
            acc[5] = fmaf(a1.y, fmaxf(x[5] + v, 0.f), acc[5]);
            acc[6] = fmaf(a1.z, fmaxf(x[6] + v, 0.f), acc[6]);
            acc[7] = fmaf(a1.w, fmaxf(x[7] + v, 0.f), acc[7]);
        }
        __syncthreads();
    }
#undef LOADTILE
#undef STORETILE

    float* accred = &adjsT[0][0];
    if (half == 1) {
#pragma unroll
        for (int r = 0; r < TI; ++r) accred[r * Dc + d] = acc[r];
    }
    __syncthreads();
    if (half == 0) {
#pragma unroll
        for (int r = 0; r < TI; ++r)
            sp[((size_t)js * BN + r0 + r) * Dc + d] = acc[r] + accred[r * Dc + d];
    }
}

// --- final second linear + residual (sums JS partials)
__global__ __launch_bounds__(128) void gnn_lin2(const float* __restrict__ hin,
                                                const float* __restrict__ sp,
                                                const float* __restrict__ arowp,
                                                const float* __restrict__ w2T,
                                                const float* __restrict__ b2,
                                                float* __restrict__ hout) {
    __shared__ float ss[TN][Dc];
    const int o = threadIdx.x;
    const int r0 = blockIdx.x * TN;
#pragma unroll
    for (int t = 0; t < TN; ++t) {
        float v = 0.f;
#pragma unroll
        for (int js = 0; js < JS; ++js) v += sp[((size_t)js * BN + r0 + t) * Dc + o];
        ss[t][o] = v;
    }
    __syncthreads();
    float acc[TN];
#pragma unroll
    for (int t = 0; t < TN; ++t) acc[t] = 0.f;
    for (int d = 0; d < Dc; d += 4) {
        float w[4];
#pragma unroll
        for (int k = 0; k < 4; ++k) w[k] = w2T[(d + k) * Dc + o];
#pragma unroll
        for (int t = 0; t < TN; ++t) {
            const float4 sv = *reinterpret_cast<const float4*>(&ss[t][d]);
            acc[t] = fmaf(sv.x, w[0], acc[t]);
            acc[t] = fmaf(sv.y, w[1], acc[t]);
            acc[t] = fmaf(sv.z, w[2], acc[t]);
            acc[t] = fmaf(sv.w, w[3], acc[t]);
        }
    }
    const float b2o = b2[o];
#pragma unroll
    for (int t = 0; t < TN; ++t) {
        float ar = 0.f;
#pragma unroll
        for (int js = 0; js < JS; ++js) ar += arowp[js * BN + r0 + t];
        hout[(r0 + t) * Dc + o] = hin[(r0 + t) * Dc + o] + acc[t] + ar * b2o;
    }
}

// --- fused: lin2 of layer l + residual, then lin1 of layer l+1
__global__ __launch_bounds__(128) void gnn_lin2lin1(const float* __restrict__ hin,
                                                    const float* __restrict__ sp,
                                                    const float* __restrict__ arowp,
                                                    const float* __restrict__ w2T,
                                                    const float* __restrict__ b2,
                                                    const float* __restrict__ wiT,
                                                    const float* __restrict__ wjT,
                                                    const float* __restrict__ b1,
                                                    float* __restrict__ hout,
                                                    float* __restrict__ ai,
                                                    float* __restrict__ aj) {
    __shared__ float ss[TN][Dc];
    const int o = threadIdx.x;
    const int r0 = blockIdx.x * TN;
#pragma unroll
    for (int t = 0; t < TN; ++t) {
        float v = 0.f;
#pragma unroll
        for (int js = 0; js < JS; ++js) v += sp[((size_t)js * BN + r0 + t) * Dc + o];
        ss[t][o] = v;
    }
    __syncthreads();
    float acc[TN];
#pragma unroll
    for (int t = 0; t < TN; ++t) acc[t] = 0.f;
    for (int d = 0; d < Dc; d += 4) {
        float w[4];
#pragma unroll
        for (int k = 0; k < 4; ++k) w[k] = w2T[(d + k) * Dc + o];
#pragma unroll
        for (int t = 0; t < TN; ++t) {
            const float4 sv = *reinterpret_cast<const float4*>(&ss[t][d]);
            acc[t] = fmaf(sv.x, w[0], acc[t]);
            acc[t] = fmaf(sv.y, w[1], acc[t]);
            acc[t] = fmaf(sv.z, w[2], acc[t]);
            acc[t] = fmaf(sv.w, w[3], acc[t]);
        }
    }
    const float b2o = b2[o];
    float hnew[TN];
#pragma unroll
    for (int t = 0; t < TN; ++t) {
        float ar = 0.f;
#pragma unroll
        for (int js = 0; js < JS; ++js) ar += arowp[js * BN + r0 + t];
        hnew[t] = hin[(r0 + t) * Dc + o] + acc[t] + ar * b2o;
        hout[(r0 + t) * Dc + o] = hnew[t];
    }
    __syncthreads();
#pragma unroll
    for (int t = 0; t < TN; ++t) ss[t][o] = hnew[t];
    __syncthreads();
    float acci[TN], accj[TN];
    const float bo = b1[o];
#pragma unroll
    for (int t = 0; t < TN; ++t) { acci[t] = bo; accj[t] = 0.f; }
    for (int d = 0; d < Dc; d += 4) {
        float wi[4], wj[4];
#pragma unroll
        for (int k = 0; k < 4; ++k) {
            wi[k] = wiT[(d + k) * Dc + o];
            wj[k] = wjT[(d + k) * Dc + o];
        }
#pragma unroll
        for (int t = 0; t < TN; ++t) {
            const float4 hv = *reinterpret_cast<const float4*>(&ss[t][d]);
            acci[t] = fmaf(hv.x, wi[0], acci[t]);
            acci[t] = fmaf(hv.y, wi[1], acci[t]);
            acci[t] = fmaf(hv.z, wi[2], acci[t]);
            acci[t] = fmaf(hv.w, wi[3], acci[t]);
            accj[t] = fmaf(hv.x, wj[0], accj[t]);
            accj[t] = fmaf(hv.y, wj[1], accj[t]);
            accj[t] = fmaf(hv.z, wj[2], accj[t]);
            accj[t] = fmaf(hv.w, wj[3], accj[t]);
        }
    }
#pragma unroll
    for (int t = 0; t < TN; ++t) {
        ai[(r0 + t) * Dc + o] = acci[t];
        aj[(r0 + t) * Dc + o] = accj[t];
    }
}

// ======================= ABLATION KERNELS (scratch output) ====================
// All: grid 1024, 256 thr, block = 2 rows, wave w owns j in [w*128,(w+1)*128).

// A: v5 streaming msg structure x AREP (VMEM stream + LDS broadcast + 12 VALU/jj)
__global__ __launch_bounds__(256) void abl_stream(const float* __restrict__ ai,
                                                  const float* __restrict__ aj,
                                                  const float* __restrict__ adj,
                                                  float* __restrict__ outp) {
    __shared__ float adjs[Nc][2];
    const int tid = threadIdx.x, w = tid >> 6, lane = tid & 63;
    const int r0 = blockIdx.x * 2, b = r0 / Nc, i0 = r0 - b * Nc;
    const float* __restrict__ ajb = aj + (size_t)b * Nc * Dc;
    const float* __restrict__ adjb = adj + (size_t)b * Nc * Nc;
    {
        const int sr = tid >> 7, sc4 = (tid & 127) * 4;
        const float4 av = *reinterpret_cast<const float4*>(&adjb[(size_t)(i0 + sr) * Nc + sc4]);
        adjs[sc4 + 0][sr] = av.x; adjs[sc4 + 1][sr] = av.y;
        adjs[sc4 + 2][sr] = av.z; adjs[sc4 + 3][sr] = av.w;
    }
    const int d0 = lane * 2;
    const float2 x0 = *reinterpret_cast<const float2*>(&ai[(size_t)r0 * Dc + d0]);
    const float2 x1 = *reinterpret_cast<const float2*>(&ai[(size_t)(r0 + 1) * Dc + d0]);
    float2 a0 = make_float2(0.f, 0.f), a1 = make_float2(0.f, 0.f);
    __syncthreads();
    const float* __restrict__ ajw = ajb + (size_t)(w * 128) * Dc + d0;
    for (int rep = 0; rep < AREP; ++rep) {
        int zoff = 0;
        asm volatile("" : "+v"(zoff));          // defeat cross-rep CSE
        const float* __restrict__ p = ajw + zoff;
#pragma unroll 8
        for (int jj = 0; jj < 128; ++jj) {
            const float2 v = *reinterpret_cast<const float2*>(&p[(size_t)jj * Dc]);
            const float2 a = *reinterpret_cast<const float2*>(&adjs[w * 128 + jj][0]);
            a0.x = fmaf(a.x, fmaxf(x0.x + v.x, 0.f), a0.x);
            a0.y = fmaf(a.x, fmaxf(x0.y + v.y, 0.f), a0.y);
            a1.x = fmaf(a.y, fmaxf(x1.x + v.x, 0.f), a1.x);
            a1.y = fmaf(a.y, fmaxf(x1.y + v.y, 0.f), a1.y);
        }
        asm volatile("" : "+v"(a0.x), "+v"(a0.y), "+v"(a1.x), "+v"(a1.y));
    }
    outp[(size_t)blockIdx.x * 256 + tid] = a0.x + a0.y + a1.x + a1.y;
}

// B: same structure, VMEM removed (register-generated v) -> VALU+LDS floor
__global__ __launch_bounds__(256) void abl_valu(const float* __restrict__ ai,
                                                const float* __restrict__ adj,
                                                float* __restrict__ outp) {
    __shared__ float adjs[Nc][2];
    const int tid = threadIdx.x, w = tid >> 6, lane = tid & 63;
    const int r0 = blockIdx.x * 2, b = r0 / Nc, i0 = r0 - b * Nc;
    const float* __restrict__ adjb = adj + (size_t)b * Nc * Nc;
    {
        const int sr = tid >> 7, sc4 = (tid & 127) * 4;
        const float4 av = *reinterpret_cast<const float4*>(&adjb[(size_t)(i0 + sr) * Nc + sc4]);
        adjs[sc4 + 0][sr] = av.x; adjs[sc4 + 1][sr] = av.y;
        adjs[sc4 + 2][sr] = av.z; adjs[sc4 + 3][sr] = av.w;
    }
    const int d0 = lane * 2;
    const float2 x0 = *reinterpret_cast<const float2*>(&ai[(size_t)r0 * Dc + d0]);
    const float2 x1 = *reinterpret_cast<const float2*>(&ai[(size_t)(r0 + 1) * Dc + d0]);
    float2 a0 = make_float2(0.f, 0.f), a1 = make_float2(0.f, 0.f);
    float vx = x0.x * 0.5f, vy = x0.y * 0.5f;
    __syncthreads();
    for (int rep = 0; rep < AREP; ++rep) {
        asm volatile("" : "+v"(vx), "+v"(vy));
#pragma unroll 8
        for (int jj = 0; jj < 128; ++jj) {
            vx = fmaf(vx, 1.0000001f, 1e-9f);
            vy = fmaf(vy, 1.0000001f, 1e-9f);
            const float2 a = *reinterpret_cast<const float2*>(&adjs[w * 128 + jj][0]);
            a0.x = fmaf(a.x, fmaxf(x0.x + vx, 0.f), a0.x);
            a0.y = fmaf(a.x, fmaxf(x0.y + vy, 0.f), a0.y);
            a1.x = fmaf(a.y, fmaxf(x1.x + vx, 0.f), a1.x);
            a1.y = fmaf(a.y, fmaxf(x1.y + vy, 0.f), a1.y);
        }
        asm volatile("" : "+v"(a0.x), "+v"(a0.y), "+v"(a1.x), "+v"(a1.y));
    }
    outp[(size_t)blockIdx.x * 256 + tid] = a0.x + a0.y + a1.x + a1.y;
}

// C: VMEM stream only -> L2 BW / latency floor
__global__ __launch_bounds__(256) void abl_l2(const float* __restrict__ aj,
                                              float* __restrict__ outp) {
    const int tid = threadIdx.x, w = tid >> 6, lane = tid & 63;
    const int r0 = blockIdx.x * 2, b = r0 / Nc;
    const float* __restrict__ ajb = aj + (size_t)b * Nc * Dc;
    const int d0 = lane * 2;
    float sx = 0.f, sy = 0.f;
    const float* __restrict__ ajw = ajb + (size_t)(w * 128) * Dc + d0;
    for (int rep = 0; rep < AREP; ++rep) {
        int zoff = 0;
        asm volatile("" : "+v"(zoff));
        const float* __restrict__ p = ajw + zoff;
#pragma unroll 8
        for (int jj = 0; jj < 128; ++jj) {
            const float2 v = *reinterpret_cast<const float2*>(&p[(size_t)jj * Dc]);
            sx += v.x;
            sy += v.y;
        }
        asm volatile("" : "+v"(sx), "+v"(sy));
    }
    outp[(size_t)blockIdx.x * 256 + tid] = sx + sy;
}

extern "C" void kernel_launch(void* const* d_in, const int* in_sizes, int n_in,
                              void* d_out, int out_size, void* d_ws, size_t ws_size,
                              hipStream_t stream) {
    const float* node = (const float*)d_in[0];
    const float* adj  = (const float*)d_in[1];
    const float* w1   = (const float*)d_in[2];
    const float* b1   = (const float*)d_in[3];
    const float* w2   = (const float*)d_in[4];
    const float* b2   = (const float*)d_in[5];
    float* out = (float*)d_out;

    float* ws = (float*)d_ws;
    float* wiT  = ws; ws += Lc * Dc * Dc;
    float* wjT  = ws; ws += Lc * Dc * Dc;
    float* w2T  = ws; ws += Lc * Dc * Dc;
    float* ai   = ws; ws += BN * Dc;
    float* aj   = ws; ws += BN * Dc;
    float* sp   = ws; ws += (size_t)JS * BN * Dc;
    float* arowp= ws; ws += JS * BN;
    float* h1   = ws; ws += BN * Dc;
    float* ablA = ws; ws += 1024 * 256;
    float* ablB = ws; ws += 1024 * 256;
    float* ablC = ws; ws += 1024 * 256;

    transpose_w_kernel<<<(Lc * Dc * Dc + 255) / 256, 256, 0, stream>>>(w1, w2, wiT, wjT, w2T);

    // layer 0
    gnn_lin1<<<BN / TN, 128, 0, stream>>>(node, wiT, wjT, b1, ai, aj);
    gnn_msg<<<(BN / TI) * JS, 256, 0, stream>>>(ai, aj, adj, sp, arowp);
    gnn_lin2lin1<<<BN / TN, 128, 0, stream>>>(node, sp, arowp, w2T, b2,
                                              wiT + Dc * Dc, wjT + Dc * Dc, b1 + Dc,
                                              h1, ai, aj);
    // layer 1
    gnn_msg<<<(BN / TI) * JS, 256, 0, stream>>>(ai, aj, adj, sp, arowp);
    gnn_lin2<<<BN / TN, 128, 0, stream>>>(h1, sp, arowp, w2T + Dc * Dc, b2 + Dc, out);

    // ---- ablations (read layer-1 ai/aj; deterministic; scratch-only writes)
    abl_stream<<<1024, 256, 0, stream>>>(ai, aj, adj, ablA);
    abl_valu<<<1024, 256, 0, stream>>>(ai, adj, ablB);
    abl_l2<<<1024, 256, 0, stream>>>(aj, ablC);
}

// Round 9
// 50.711 us; speedup vs baseline: 13.5910x; 13.5910x over previous
//
#include <hip/hip_runtime.h>

// SimpleGNN: B=4, N=512, D=128, L=2
// msg[b,i,:] = (sum_j adj[b,i,j]*relu(ai'[b,i,:]+aj[b,j,:])) @ w2^T
//            + (sum_j adj[b,i,j]) * b2 ;  ai' = h@wi^T + b1, aj = h@wj^T
//
// Round-8 ablation: msg structure is VALU-issue-bound (58% busy, 17.4us/msg,
// ~2x instr bloat from per-j addressing). v6 fixes arithmetic density:
//   - float4 loads cover 2 j's per instr (lane jlane=lane>>5 picks j parity)
//   - 4 rows/block: 48 useful VALU per load (1.17x bloat)
//   - streaming from L2 (confirmed not BW-bound), no intra-block pipelining
// Plus dispatch fusion: msg + lin2 + residual (+ next lin1) in ONE kernel.
// 4 dispatches total.

constexpr int Bc = 4, Nc = 512, Dc = 128, Lc = 2;
constexpr int BN = Bc * Nc;  // 2048
constexpr int TIB = 4;       // rows per msgfull block
constexpr int TN = 4;        // rows per lin block

// --- weight transpose: wiT[l][d][o], wjT[l][d][o], w2T[l][d][o]
__global__ void transpose_w_kernel(const float* __restrict__ w1,
                                   const float* __restrict__ w2,
                                   float* __restrict__ wiT,
                                   float* __restrict__ wjT,
                                   float* __restrict__ w2T) {
    int idx = blockIdx.x * blockDim.x + threadIdx.x;
    if (idx >= Lc * Dc * Dc) return;
    int l = idx / (Dc * Dc);
    int rem = idx - l * Dc * Dc;
    int d = rem / Dc;
    int o = rem - d * Dc;
    wiT[idx] = w1[(l * Dc + o) * (2 * Dc) + d];
    wjT[idx] = w1[(l * Dc + o) * (2 * Dc) + Dc + d];
    w2T[idx] = w2[(l * Dc + o) * Dc + d];
}

// --- first linear (round-3 winner, verbatim)
__global__ __launch_bounds__(128) void gnn_lin1(const float* __restrict__ h,
                                                const float* __restrict__ wiT,
                                                const float* __restrict__ wjT,
                                                const float* __restrict__ b1,
                                                float* __restrict__ ai,
                                                float* __restrict__ aj) {
    __shared__ float hs[TN][Dc];
    const int o = threadIdx.x;
    const int r0 = blockIdx.x * TN;
#pragma unroll
    for (int t = 0; t < TN; ++t) hs[t][o] = h[(r0 + t) * Dc + o];
    __syncthreads();
    float acci[TN], accj[TN];
    const float bo = b1[o];
#pragma unroll
    for (int t = 0; t < TN; ++t) { acci[t] = bo; accj[t] = 0.f; }
    for (int d = 0; d < Dc; d += 4) {
        float wi[4], wj[4];
#pragma unroll
        for (int k = 0; k < 4; ++k) {
            wi[k] = wiT[(d + k) * Dc + o];
            wj[k] = wjT[(d + k) * Dc + o];
        }
#pragma unroll
        for (int t = 0; t < TN; ++t) {
            const float4 hv = *reinterpret_cast<const float4*>(&hs[t][d]);
            acci[t] = fmaf(hv.x, wi[0], acci[t]);
            acci[t] = fmaf(hv.y, wi[1], acci[t]);
            acci[t] = fmaf(hv.z, wi[2], acci[t]);
            acci[t] = fmaf(hv.w, wi[3], acci[t]);
            accj[t] = fmaf(hv.x, wj[0], accj[t]);
            accj[t] = fmaf(hv.y, wj[1], accj[t]);
            accj[t] = fmaf(hv.z, wj[2], accj[t]);
            accj[t] = fmaf(hv.w, wj[3], accj[t]);
        }
    }
#pragma unroll
    for (int t = 0; t < TN; ++t) {
        ai[(r0 + t) * Dc + o] = acci[t];
        aj[(r0 + t) * Dc + o] = accj[t];
    }
}

// --- fused msg(v6) + lin2 + residual (+ lin1 of next layer).
// grid = BN/TIB = 512 blocks, 512 thr (8 waves). Wave w streams j in
// [w*64, w*64+64) as 32 float4 loads (2 j's each).
template <bool HAS_NEXT>
__global__ __launch_bounds__(512) void gnn_msgfull(
    const float* __restrict__ ai, const float* __restrict__ aj,
    const float* __restrict__ adj, const float* __restrict__ hin,
    const float* __restrict__ w2T, const float* __restrict__ b2,
    const float* __restrict__ wiT, const float* __restrict__ wjT,
    const float* __restrict__ b1, float* __restrict__ hout,
    float* __restrict__ ai_out, float* __restrict__ aj_out) {
    __shared__ __align__(16) float adjs[TIB][Nc];   // 8 KB  [r][j]
    __shared__ __align__(16) float scratch[4096];   // 16 KB (sred / GEMV partials)
    __shared__ float s_lds[TIB][Dc];                // 2 KB
    __shared__ float hnew_lds[TIB][Dc];             // 2 KB
    __shared__ float redw[8];

    const int tid = threadIdx.x;
    const int w = tid >> 6;
    const int lane = tid & 63;
    const int r0 = blockIdx.x * TIB;
    const int b = r0 >> 9;        // / Nc
    const int i0 = r0 & (Nc - 1);
    const float* __restrict__ ajb = aj + (size_t)b * Nc * Dc;
    const float* __restrict__ adjb = adj + (size_t)b * Nc * Nc;

    // ---- stage adjs [r][j] (coalesced) + arow wave partials
    {
        const int rr = tid >> 7;          // 0..3
        const int c4 = (tid & 127) * 4;
        const float4 av =
            *reinterpret_cast<const float4*>(&adjb[(size_t)(i0 + rr) * Nc + c4]);
        *reinterpret_cast<float4*>(&adjs[rr][c4]) = av;
        float p = av.x + av.y + av.z + av.w;
#pragma unroll
        for (int m = 32; m >= 1; m >>= 1) p += __shfl_xor(p, m);
        if (lane == 0) redw[w] = p;       // row (w>>1), col-half (w&1)
    }

    // ---- per-lane stream state: j-parity jlane, d-quad dq
    const int jlane = lane >> 5;          // 0/1
    const int dq = (lane & 31) * 4;       // 0..124
    float4 x[TIB], acc[TIB];
#pragma unroll
    for (int r = 0; r < TIB; ++r) {
        x[r] = *reinterpret_cast<const float4*>(&ai[(size_t)(r0 + r) * Dc + dq]);
        acc[r] = make_float4(0.f, 0.f, 0.f, 0.f);
    }
    __syncthreads();

    // ---- stream: 32 iters x (1 float4 VMEM + 4 LDS b32 + 48 VALU)
    const int jw = w * 64;
    const float* __restrict__ pbase = ajb + (size_t)(jw + jlane) * Dc + dq;
#pragma unroll 4
    for (int it = 0; it < 32; ++it) {
        const float4 v = *reinterpret_cast<const float4*>(pbase + (size_t)it * 256);
        const int j = jw + 2 * it + jlane;
        const float a0 = adjs[0][j];
        const float a1 = adjs[1][j];
        const float a2 = adjs[2][j];
        const float a3 = adjs[3][j];
#define ROWF(r, a)                                                       \
        acc[r].x = fmaf(a, fmaxf(x[r].x + v.x, 0.f), acc[r].x);          \
        acc[r].y = fmaf(a, fmaxf(x[r].y + v.y, 0.f), acc[r].y);          \
        acc[r].z = fmaf(a, fmaxf(x[r].z + v.z, 0.f), acc[r].z);          \
        acc[r].w = fmaf(a, fmaxf(x[r].w + v.w, 0.f), acc[r].w);
        ROWF(0, a0) ROWF(1, a1) ROWF(2, a2) ROWF(3, a3)
#undef ROWF
    }

    // ---- merge j-parity halves, park per-wave partials in scratch
#pragma unroll
    for (int r = 0; r < TIB; ++r) {
        acc[r].x += __shfl_xor(acc[r].x, 32);
        acc[r].y += __shfl_xor(acc[r].y, 32);
        acc[r].z += __shfl_xor(acc[r].z, 32);
        acc[r].w += __shfl_xor(acc[r].w, 32);
    }
    if (lane < 32) {
#pragma unroll
        for (int r = 0; r < TIB; ++r)
            *reinterpret_cast<float4*>(&scratch[w * 512 + r * 128 + dq]) = acc[r];
    }
    __syncthreads();

    // ---- reduce 8 wave-partials -> s_lds
    {
        const int rr = tid >> 7;
        const int dd = tid & 127;
        float s = 0.f;
#pragma unroll
        for (int ww = 0; ww < 8; ++ww) s += scratch[ww * 512 + rr * 128 + dd];
        s_lds[rr][dd] = s;
    }
    __syncthreads();

    // ---- lin2 GEMV, d-sliced: thread (o, g) does d in [g*32, g*32+32) for all rows
    {
        const int o = tid & 127;
        const int g = tid >> 7;
        float part[TIB] = {0.f, 0.f, 0.f, 0.f};
        for (int dd = g * 32; dd < g * 32 + 32; dd += 4) {
            float wv[4];
#pragma unroll
            for (int k = 0; k < 4; ++k) wv[k] = w2T[(size_t)(dd + k) * Dc + o];
#pragma unroll
            for (int r = 0; r < TIB; ++r) {
                const float4 sv = *reinterpret_cast<const float4*>(&s_lds[r][dd]);
                part[r] = fmaf(sv.x, wv[0], part[r]);
                part[r] = fmaf(sv.y, wv[1], part[r]);
                part[r] = fmaf(sv.z, wv[2], part[r]);
                part[r] = fmaf(sv.w, wv[3], part[r]);
            }
        }
#pragma unroll
        for (int r = 0; r < TIB; ++r) scratch[g * 512 + r * 128 + o] = part[r];
    }
    __syncthreads();

    // ---- combine partials + residual + b2*arow -> hnew
    {
        const int rr = tid >> 7;
        const int o = tid & 127;
        float a2c = scratch[rr * 128 + o] + scratch[512 + rr * 128 + o] +
                    scratch[1024 + rr * 128 + o] + scratch[1536 + rr * 128 + o];
        const float arow_r = redw[2 * rr] + redw[2 * rr + 1];
        const float hn =
            hin[(size_t)(r0 + rr) * Dc + o] + a2c + arow_r * b2[o];
        hout[(size_t)(r0 + rr) * Dc + o] = hn;
        if constexpr (HAS_NEXT) hnew_lds[rr][o] = hn;
    }

    if constexpr (HAS_NEXT) {
        __syncthreads();
        // ---- lin1 of next layer (wi and wj GEMVs), d-sliced
        {
            const int o = tid & 127;
            const int g = tid >> 7;
            float pi[TIB] = {0.f, 0.f, 0.f, 0.f};
            float pj[TIB] = {0.f, 0.f, 0.f, 0.f};
            for (int dd = g * 32; dd < g * 32 + 32; dd += 4) {
                float wiv[4], wjv[4];
#pragma unroll
                for (int k = 0; k < 4; ++k) {
                    wiv[k] = wiT[(size_t)(dd + k) * Dc + o];
                    wjv[k] = wjT[(size_t)(dd + k) * Dc + o];
                }
#pragma unroll
                for (int r = 0; r < TIB; ++r) {
                    const float4 hv =
                        *reinterpret_cast<const float4*>(&hnew_lds[r][dd]);
                    pi[r] = fmaf(hv.x, wiv[0], pi[r]);
                    pi[r] = fmaf(hv.y, wiv[1], pi[r]);
                    pi[r] = fmaf(hv.z, wiv[2], pi[r]);
                    pi[r] = fmaf(hv.w, wiv[3], pi[r]);
                    pj[r] = fmaf(hv.x, wjv[0], pj[r]);
                    pj[r] = fmaf(hv.y, wjv[1], pj[r]);
                    pj[r] = fmaf(hv.z, wjv[2], pj[r]);
                    pj[r] = fmaf(hv.w, wjv[3], pj[r]);
                }
            }
#pragma unroll
            for (int r = 0; r < TIB; ++r) {
                scratch[g * 512 + r * 128 + o] = pi[r];
                scratch[2048 + g * 512 + r * 128 + o] = pj[r];
            }
        }
        __syncthreads();
        {
            const int rr = tid >> 7;
            const int o = tid & 127;
            float acci = b1[o];
            float accj = 0.f;
#pragma unroll
            for (int g = 0; g < 4; ++g) {
                acci += scratch[g * 512 + rr * 128 + o];
                accj += scratch[2048 + g * 512 + rr * 128 + o];
            }
            ai_out[(size_t)(r0 + rr) * Dc + o] = acci;
            aj_out[(size_t)(r0 + rr) * Dc + o] = accj;
        }
    }
}

extern "C" void kernel_launch(void* const* d_in, const int* in_sizes, int n_in,
                              void* d_out, int out_size, void* d_ws, size_t ws_size,
                              hipStream_t stream) {
    const float* node = (const float*)d_in[0];
    const float* adj  = (const float*)d_in[1];
    const float* w1   = (const float*)d_in[2];
    const float* b1   = (const float*)d_in[3];
    const float* w2   = (const float*)d_in[4];
    const float* b2   = (const float*)d_in[5];
    float* out = (float*)d_out;

    float* ws = (float*)d_ws;
    float* wiT = ws; ws += Lc * Dc * Dc;
    float* wjT = ws; ws += Lc * Dc * Dc;
    float* w2T = ws; ws += Lc * Dc * Dc;
    float* ai  = ws; ws += BN * Dc;
    float* aj  = ws; ws += BN * Dc;
    float* ai2 = ws; ws += BN * Dc;
    float* aj2 = ws; ws += BN * Dc;
    float* h1  = ws; ws += BN * Dc;

    transpose_w_kernel<<<(Lc * Dc * Dc + 255) / 256, 256, 0, stream>>>(
        w1, w2, wiT, wjT, w2T);

    // layer 0: lin1, then fused msg+lin2+residual+lin1(layer1)
    gnn_lin1<<<BN / TN, 128, 0, stream>>>(node, wiT, wjT, b1, ai, aj);
    gnn_msgfull<true><<<BN / TIB, 512, 0, stream>>>(
        ai, aj, adj, node, w2T, b2, wiT + Dc * Dc, wjT + Dc * Dc, b1 + Dc,
        h1, ai2, aj2);
    // layer 1: fused msg+lin2+residual -> out
    gnn_msgfull<false><<<BN / TIB, 512, 0, stream>>>(
        ai2, aj2, adj, h1, w2T + Dc * Dc, b2 + Dc, nullptr, nullptr, nullptr,
        out, nullptr, nullptr);
}